// Round 2
// baseline (355.145 us; speedup 1.0000x reference)
//
#include <hip/hip_runtime.h>
#include <hip/hip_bf16.h>

// ConformerAttention on MI355X (gfx950), bf16 MFMA internal, fp32 in/out.
// rel_shift(ps)[i,j] == ps[i, j-i+S-1]  -> banded pos-score, never materialize [S,P].
// R2: V produced transposed (vt[d][token]) by fused QKV GEMM -> attention has zero
//     __syncthreads (all LDS wave-private) and zero LDS transpose conflicts.

typedef __attribute__((ext_vector_type(8))) short  s16x8;
typedef __attribute__((ext_vector_type(4))) short  s16x4;
typedef __attribute__((ext_vector_type(8))) __bf16 bfv8;
typedef __attribute__((ext_vector_type(4))) float  f32x4;

__device__ __forceinline__ float b2f(short s){
  unsigned u = ((unsigned)(unsigned short)s) << 16;
  float f; __builtin_memcpy(&f, &u, 4); return f;
}
__device__ __forceinline__ short f2b(float f){
  unsigned u; __builtin_memcpy(&u, &f, 4);
  u = (u + 0x7fffu + ((u >> 16) & 1u)) >> 16;
  return (short)u;
}
__device__ __forceinline__ f32x4 MFMA(s16x8 a, s16x8 b, f32x4 c){
  return __builtin_amdgcn_mfma_f32_16x16x32_bf16(
      __builtin_bit_cast(bfv8, a), __builtin_bit_cast(bfv8, b), c, 0, 0, 0);
}
__device__ __forceinline__ void gload_lds16(const void* g, void* l){
  __builtin_amdgcn_global_load_lds(
      (const __attribute__((address_space(1))) void*)g,
      (__attribute__((address_space(3))) void*)l, 16, 0, 0);
}
__device__ __forceinline__ void cvt8(const float* in, short* out, size_t i8){
  f32x4 a = *(const f32x4*)(in + i8*8);
  f32x4 b = *(const f32x4*)(in + i8*8 + 4);
  short o[8];
  o[0]=f2b(a[0]); o[1]=f2b(a[1]); o[2]=f2b(a[2]); o[3]=f2b(a[3]);
  o[4]=f2b(b[0]); o[5]=f2b(b[1]); o[6]=f2b(b[2]); o[7]=f2b(b[3]);
  *(s16x8*)(out + i8*8) = *(s16x8*)o;
}

// ---- fused f32->bf16 converts: 5 weights (stacked Wq/Wk/Wv + Wo + Wp) + pos ----
__global__ __launch_bounds__(256) void cvt_all(
    const float* __restrict__ Wq, const float* __restrict__ Wk,
    const float* __restrict__ Wv, const float* __restrict__ Wo,
    const float* __restrict__ Wp, const float* __restrict__ pos,
    short* __restrict__ wqkv, short* __restrict__ wo,
    short* __restrict__ wp, short* __restrict__ posbf)
{
  int bid = blockIdx.x, tid = threadIdx.x;
  if(bid < 640){
    int w = bid >> 7;
    size_t i = (size_t)(bid & 127)*256 + tid;   // < 32768 per weight
    const float* src; short* dst;
    if(w == 0){ src = Wq; dst = wqkv; }
    else if(w == 1){ src = Wk; dst = wqkv + 262144; }
    else if(w == 2){ src = Wv; dst = wqkv + 524288; }
    else if(w == 3){ src = Wo; dst = wo; }
    else { src = Wp; dst = wp; }
    cvt8(src, dst, i);
  } else {
    size_t i = (size_t)(bid - 640)*256 + tid;
    if(i < 131008) cvt8(pos, posbf, i);        // 2047*512/8
  }
}

// ---- LayerNorm: 4 waves/block, one wave per row of 512, bf16 out ----
__global__ __launch_bounds__(256) void ln_kernel(const float* __restrict__ x,
    const float* __restrict__ w, const float* __restrict__ b, short* __restrict__ out){
  int row = blockIdx.x*4 + (threadIdx.x >> 6);
  int lane = threadIdx.x & 63;
  const float* xr = x + (size_t)row*512;
  f32x4 v0 = *(const f32x4*)(xr + lane*8);
  f32x4 v1 = *(const f32x4*)(xr + lane*8 + 4);
  float s  = v0[0]+v0[1]+v0[2]+v0[3]+v1[0]+v1[1]+v1[2]+v1[3];
  float s2 = v0[0]*v0[0]+v0[1]*v0[1]+v0[2]*v0[2]+v0[3]*v0[3]
           + v1[0]*v1[0]+v1[1]*v1[1]+v1[2]*v1[2]+v1[3]*v1[3];
  #pragma unroll
  for(int m=1;m<64;m<<=1){ s += __shfl_xor(s,m); s2 += __shfl_xor(s2,m); }
  float mu = s * (1.0f/512.0f);
  float rs = rsqrtf(s2*(1.0f/512.0f) - mu*mu + 1e-5f);
  short o[8];
  #pragma unroll
  for(int e=0;e<8;e++){
    float xv = (e<4)? v0[e] : v1[e-4];
    int d = lane*8 + e;
    o[e] = f2b((xv - mu)*rs*w[d] + b[d]);
  }
  *(s16x8*)(out + (size_t)row*512 + lane*8) = *(s16x8*)o;
}

// ---- generic GEMM: C[M,N] = A[M,K] @ B[N,K]^T (+bias) (+resid fp32 out) ----
template<int MODE>  // 0: bf16 out (+bias), 1: fp32 out (+bias+resid)
__global__ __launch_bounds__(256) void gemm_bt(
    const short* __restrict__ A, const short* __restrict__ B,
    const float* __restrict__ bias, const float* __restrict__ resid,
    void* __restrict__ Cout, int M, int N, int K, int Aclamp)
{
  __shared__ __align__(16) short At[128*32];
  __shared__ __align__(16) short Bt[128*32];
  int tid = threadIdx.x;
  int wave = tid >> 6, lane = tid & 63;
  int quad = lane >> 4, l16 = lane & 15;
  int wm = wave >> 1, wn = wave & 1;
  int m0 = blockIdx.y*128, n0 = blockIdx.x*128;
  int srow = lane >> 2, scol = (lane & 3)*8;
  f32x4 acc[4][4] = {};
  for(int k0=0; k0<K; k0+=32){
    #pragma unroll
    for(int c=0;c<2;c++){
      int r = wave*32 + c*16 + srow;
      int ra = m0 + r; if(ra > Aclamp-1) ra = Aclamp-1;
      gload_lds16(A + (size_t)ra*K + k0 + scol, At + (wave*32 + c*16)*32);
      gload_lds16(B + (size_t)(n0 + r)*K + k0 + scol, Bt + (wave*32 + c*16)*32);
    }
    __syncthreads();
    s16x8 af[4], bfr[4];
    #pragma unroll
    for(int i=0;i<4;i++) af[i]  = *(const s16x8*)(At + (wm*64 + i*16 + l16)*32 + quad*8);
    #pragma unroll
    for(int j=0;j<4;j++) bfr[j] = *(const s16x8*)(Bt + (wn*64 + j*16 + l16)*32 + quad*8);
    #pragma unroll
    for(int i=0;i<4;i++)
      #pragma unroll
      for(int j=0;j<4;j++)
        acc[i][j] = MFMA(af[i], bfr[j], acc[i][j]);
    __syncthreads();
  }
  #pragma unroll
  for(int i=0;i<4;i++){
    int rowb = m0 + wm*64 + i*16 + quad*4;
    #pragma unroll
    for(int j=0;j<4;j++){
      int col = n0 + wn*64 + j*16 + l16;
      float bv = bias ? bias[col] : 0.0f;
      #pragma unroll
      for(int r=0;r<4;r++){
        size_t idx = (size_t)(rowb + r)*N + col;
        float v = acc[i][j][r] + bv;
        if(MODE == 0) ((short*)Cout)[idx] = f2b(v);
        else          ((float*)Cout)[idx] = v + resid[idx];
      }
    }
  }
}

// ---- fused QKV GEMM: C[8192,1536] = h @ [Wq;Wk;Wv]^T + b ----
// seg 0 -> q[t*512+c], seg 1 -> k[t*512+c], seg 2 -> vt[c*8192+t] (transposed!)
__global__ __launch_bounds__(256) void gemm_qkv(
    const short* __restrict__ A, const short* __restrict__ B,
    const float* __restrict__ bq, const float* __restrict__ bk,
    const float* __restrict__ bv,
    short* __restrict__ qo, short* __restrict__ ko, short* __restrict__ vto)
{
  __shared__ __align__(16) short At[128*32];
  __shared__ __align__(16) short Bt[128*32];
  int tid = threadIdx.x;
  int wave = tid >> 6, lane = tid & 63;
  int quad = lane >> 4, l16 = lane & 15;
  int wm = wave >> 1, wn = wave & 1;
  int m0 = blockIdx.y*128, n0 = blockIdx.x*128;
  int srow = lane >> 2, scol = (lane & 3)*8;
  f32x4 acc[4][4] = {};
  for(int k0=0; k0<512; k0+=32){
    #pragma unroll
    for(int c=0;c<2;c++){
      int r = wave*32 + c*16 + srow;
      gload_lds16(A + (size_t)(m0 + r)*512 + k0 + scol, At + (wave*32 + c*16)*32);
      gload_lds16(B + (size_t)(n0 + r)*512 + k0 + scol, Bt + (wave*32 + c*16)*32);
    }
    __syncthreads();
    s16x8 af[4], bfr[4];
    #pragma unroll
    for(int i=0;i<4;i++) af[i]  = *(const s16x8*)(At + (wm*64 + i*16 + l16)*32 + quad*8);
    #pragma unroll
    for(int j=0;j<4;j++) bfr[j] = *(const s16x8*)(Bt + (wn*64 + j*16 + l16)*32 + quad*8);
    #pragma unroll
    for(int i=0;i<4;i++)
      #pragma unroll
      for(int j=0;j<4;j++)
        acc[i][j] = MFMA(af[i], bfr[j], acc[i][j]);
    __syncthreads();
  }
  #pragma unroll
  for(int i=0;i<4;i++){
    int rowb = m0 + wm*64 + i*16 + quad*4;
    #pragma unroll
    for(int j=0;j<4;j++){
      int colg = n0 + wn*64 + j*16 + l16;
      int seg = colg >> 9, c = colg & 511;
      float bias = (seg == 0) ? bq[c] : (seg == 1) ? bk[c] : bv[c];
      if(seg < 2){
        short* dst = seg ? ko : qo;
        #pragma unroll
        for(int r=0;r<4;r++)
          dst[(size_t)(rowb + r)*512 + c] = f2b(acc[i][j][r] + bias);
      } else {
        short o4[4];
        #pragma unroll
        for(int r=0;r<4;r++) o4[r] = f2b(acc[i][j][r] + bias);
        *(s16x4*)(vto + (size_t)c*8192 + rowb) = *(s16x4*)o4;
      }
    }
  }
}

// ---- Fused rel-pos attention, zero barriers ----
// grid(16 qtiles, 8 heads, 8 batch), 256 thr = 4 waves, 16 q-rows/wave.
// score(i,j) = [(q_i+u)·k_j + (q_i+v)·p_{j-i+1023}] / 8 ; online softmax ; O = P@V.
// V fragments read directly from global vt[d_global][token]; all LDS wave-private.
__global__ __launch_bounds__(256) void attn_kernel(
    const short* __restrict__ q, const short* __restrict__ k, const short* __restrict__ vt,
    const short* __restrict__ p, const float* __restrict__ bu, const float* __restrict__ bvv,
    short* __restrict__ out)
{
  __shared__ __align__(16) float ps_lds[4][16*84];  // per-wave banded pos scores
  __shared__ __align__(16) short p_lds[4][16*72];   // per-wave P tile (A-layout src)
  int tid = threadIdx.x;
  int wave = tid >> 6, lane = tid & 63, quad = lane >> 4, l16 = lane & 15;
  int qt = blockIdx.x, h = blockIdx.y, b = blockIdx.z;
  int iw = qt*64 + wave*16;

  // q fragments with bias_u / bias_v folded in (A-layout, 2 k-steps of 32)
  size_t qbase = ((size_t)(b*1024 + iw + l16)*512) + h*64;
  s16x8 qu[2], qv[2];
  #pragma unroll
  for(int ks=0;ks<2;ks++){
    s16x8 qr = *(const s16x8*)(q + qbase + ks*32 + quad*8);
    short tu[8], tv[8];
    #pragma unroll
    for(int e=0;e<8;e++){
      int d = h*64 + ks*32 + quad*8 + e;
      float f = b2f(qr[e]);
      tu[e] = f2b(f + bu[d]);
      tv[e] = f2b(f + bvv[d]);
    }
    qu[ks] = *(s16x8*)tu; qv[ks] = *(s16x8*)tv;
  }

  f32x4 oacc[4] = {};
  float mrow[4], lrow[4];
  #pragma unroll
  for(int r=0;r<4;r++){ mrow[r] = -1e30f; lrow[r] = 0.0f; }
  float* psw = ps_lds[wave];
  short* pw  = p_lds[wave];

  const short* kb  = k  + ((size_t)b*1024)*512 + h*64;
  const short* vtb = vt + ((size_t)h*64)*8192 + b*1024;

  for(int jt=0; jt<16; jt++){
    int j0 = jt*64;
    // content scores: 4 j-subtiles x 2 k-steps (k direct from global)
    f32x4 sc[4];
    #pragma unroll
    for(int js=0;js<4;js++){
      f32x4 a = {};
      #pragma unroll
      for(int ks=0;ks<2;ks++){
        s16x8 kf = *(const s16x8*)(kb + (size_t)(j0 + js*16 + l16)*512 + ks*32 + quad*8);
        a = MFMA(qu[ks], kf, a);
      }
      sc[js] = a;
    }
    // banded pos scores: r window [r0, r0+79], r0 in [0,1968], reads < 2048 (padded p)
    int r0 = j0 - iw + 1008;
    #pragma unroll
    for(int nt=0;nt<5;nt++){
      f32x4 a = {};
      #pragma unroll
      for(int ks=0;ks<2;ks++){
        s16x8 pf = *(const s16x8*)(p + ((size_t)(r0 + nt*16 + l16)*512) + h*64 + ks*32 + quad*8);
        a = MFMA(qv[ks], pf, a);
      }
      #pragma unroll
      for(int r=0;r<4;r++) psw[(quad*4+r)*84 + nt*16 + l16] = a[r];
    }
    // gather band (r_local = jl - il + 15), combine, online softmax (wave-local)
    float pvals[4][4];
    #pragma unroll
    for(int r=0;r<4;r++){
      int il = quad*4 + r;
      float mx = -1e30f;
      #pragma unroll
      for(int js=0;js<4;js++){
        int jl = js*16 + l16;
        float sv = (sc[js][r] + psw[il*84 + (jl - il + 15)]) * 0.125f;
        pvals[js][r] = sv;
        mx = fmaxf(mx, sv);
      }
      #pragma unroll
      for(int m=1;m<16;m<<=1) mx = fmaxf(mx, __shfl_xor(mx, m));
      float mn = fmaxf(mrow[r], mx);
      float alpha = __expf(mrow[r] - mn);
      mrow[r] = mn;
      float ls = 0.0f;
      #pragma unroll
      for(int js=0;js<4;js++){
        float pe = __expf(pvals[js][r] - mn);
        pvals[js][r] = pe;
        ls += pe;
      }
      #pragma unroll
      for(int m=1;m<16;m<<=1) ls += __shfl_xor(ls, m);
      lrow[r] = lrow[r]*alpha + ls;
      #pragma unroll
      for(int ds=0;ds<4;ds++) oacc[ds][r] *= alpha;
    }
    // P -> LDS in PV A-layout source form (wave-local)
    #pragma unroll
    for(int js=0;js<4;js++)
      #pragma unroll
      for(int r=0;r<4;r++)
        pw[(quad*4+r)*72 + js*16 + l16] = f2b(pvals[js][r]);
    // PV: 2 j-ksteps x 4 d-subtiles, V^T fragments direct from global
    #pragma unroll
    for(int jk=0;jk<2;jk++){
      s16x8 pf = *(const s16x8*)(pw + l16*72 + jk*32 + quad*8);
      #pragma unroll
      for(int ds=0;ds<4;ds++){
        s16x8 vf = *(const s16x8*)(vtb + (size_t)(ds*16 + l16)*8192 + j0 + jk*32 + quad*8);
        oacc[ds] = MFMA(pf, vf, oacc[ds]);
      }
    }
  }
  // epilogue: normalize, write bf16 [B,S,H,hd] == [8192,512]
  #pragma unroll
  for(int ds=0; ds<4; ds++){
    #pragma unroll
    for(int r=0;r<4;r++){
      int il = quad*4 + r;
      float ov = oacc[ds][r] / lrow[r];
      out[((size_t)(b*1024 + iw + il)*512) + h*64 + ds*16 + l16] = f2b(ov);
    }
  }
}

extern "C" void kernel_launch(void* const* d_in, const int* in_sizes, int n_in,
                              void* d_out, int out_size, void* d_ws, size_t ws_size,
                              hipStream_t stream)
{
  const float* x    = (const float*)d_in[0];
  const float* pos  = (const float*)d_in[1];
  const float* lnw  = (const float*)d_in[2];
  const float* lnb  = (const float*)d_in[3];
  const float* Wq   = (const float*)d_in[4];
  const float* bq   = (const float*)d_in[5];
  const float* Wk   = (const float*)d_in[6];
  const float* bk   = (const float*)d_in[7];
  const float* Wv   = (const float*)d_in[8];
  const float* bv   = (const float*)d_in[9];
  const float* Wo   = (const float*)d_in[10];
  const float* bo   = (const float*)d_in[11];
  const float* Wp   = (const float*)d_in[12];
  const float* pbu  = (const float*)d_in[13];
  const float* pbv  = (const float*)d_in[14];
  float* out = (float*)d_out;

  char* ws = (char*)d_ws;
  short* h_bf    = (short*)(ws);                       // 8192x512
  short* q_bf    = (short*)(ws + ( 8u<<20));
  short* k_bf    = (short*)(ws + (16u<<20));
  short* vt_bf   = (short*)(ws + (24u<<20));           // [512][8192] transposed V
  short* a_bf    = (short*)(ws + (32u<<20));
  short* p_bf    = (short*)(ws + (40u<<20));           // 2048x512 (padded)
  short* pos_bf  = (short*)(ws + (42u<<20));           // 2047x512
  short* wqkv_bf = (short*)(ws + (44u<<20));           // [1536][512] stacked
  short* wo_bf   = (short*)(ws + (46u<<20));
  short* wp_bf   = (short*)(ws + (47u<<20));

  cvt_all<<<dim3(1152), 256, 0, stream>>>(Wq, Wk, Wv, Wo, Wp, pos,
                                          wqkv_bf, wo_bf, wp_bf, pos_bf);
  ln_kernel<<<dim3(2048), 256, 0, stream>>>(x, lnw, lnb, h_bf);
  gemm_qkv<<<dim3(12,64), 256, 0, stream>>>(h_bf, wqkv_bf, bq, bk, bv,
                                            q_bf, k_bf, vt_bf);
  gemm_bt<0><<<dim3(4,16), 256, 0, stream>>>(pos_bf, wp_bf, nullptr, nullptr,
                                             p_bf, 2048,512,512, 2047);
  attn_kernel<<<dim3(16,8,8), 256, 0, stream>>>(q_bf, k_bf, vt_bf, p_bf, pbu, pbv, a_bf);
  gemm_bt<1><<<dim3(4,64), 256, 0, stream>>>(a_bf, wo_bf, bo, x, out, 8192,512,512, 8192);
  (void)in_sizes; (void)n_in; (void)out_size; (void)ws_size;
}

// Round 3
// 276.211 us; speedup vs baseline: 1.2858x; 1.2858x over previous
//
#include <hip/hip_runtime.h>
#include <hip/hip_bf16.h>

// ConformerAttention on MI355X (gfx950), bf16 MFMA internal, fp32 in/out.
// rel_shift(ps)[i,j] == ps[i, j-i+S-1]  -> banded pos-score, never materialize [S,P].
// R3: fragment-major pre-swizzled k_sw/p_sw/v_sw so every attention global load is
//     a fully coalesced 1KB wave load. Attention: zero barriers, wave-private LDS.

typedef __attribute__((ext_vector_type(8))) short  s16x8;
typedef __attribute__((ext_vector_type(8))) __bf16 bfv8;
typedef __attribute__((ext_vector_type(4))) float  f32x4;

__device__ __forceinline__ float b2f(short s){
  unsigned u = ((unsigned)(unsigned short)s) << 16;
  float f; __builtin_memcpy(&f, &u, 4); return f;
}
__device__ __forceinline__ short f2b(float f){
  unsigned u; __builtin_memcpy(&u, &f, 4);
  u = (u + 0x7fffu + ((u >> 16) & 1u)) >> 16;
  return (short)u;
}
__device__ __forceinline__ f32x4 MFMA(s16x8 a, s16x8 b, f32x4 c){
  return __builtin_amdgcn_mfma_f32_16x16x32_bf16(
      __builtin_bit_cast(bfv8, a), __builtin_bit_cast(bfv8, b), c, 0, 0, 0);
}
__device__ __forceinline__ void gload_lds16(const void* g, void* l){
  __builtin_amdgcn_global_load_lds(
      (const __attribute__((address_space(1))) void*)g,
      (__attribute__((address_space(3))) void*)l, 16, 0, 0);
}
__device__ __forceinline__ void cvt8(const float* in, short* out, size_t i8){
  f32x4 a = *(const f32x4*)(in + i8*8);
  f32x4 b = *(const f32x4*)(in + i8*8 + 4);
  short o[8];
  o[0]=f2b(a[0]); o[1]=f2b(a[1]); o[2]=f2b(a[2]); o[3]=f2b(a[3]);
  o[4]=f2b(b[0]); o[5]=f2b(b[1]); o[6]=f2b(b[2]); o[7]=f2b(b[3]);
  *(s16x8*)(out + i8*8) = *(s16x8*)o;
}

// ---- fused f32->bf16 converts ----
__global__ __launch_bounds__(256) void cvt_all(
    const float* __restrict__ Wq, const float* __restrict__ Wk,
    const float* __restrict__ Wv, const float* __restrict__ Wo,
    const float* __restrict__ Wp, const float* __restrict__ pos,
    short* __restrict__ wqkv, short* __restrict__ wo,
    short* __restrict__ wp, short* __restrict__ posbf)
{
  int bid = blockIdx.x, tid = threadIdx.x;
  if(bid < 640){
    int w = bid >> 7;
    size_t i = (size_t)(bid & 127)*256 + tid;
    const float* src; short* dst;
    if(w == 0){ src = Wq; dst = wqkv; }
    else if(w == 1){ src = Wk; dst = wqkv + 262144; }
    else if(w == 2){ src = Wv; dst = wqkv + 524288; }
    else if(w == 3){ src = Wo; dst = wo; }
    else { src = Wp; dst = wp; }
    cvt8(src, dst, i);
  } else {
    size_t i = (size_t)(bid - 640)*256 + tid;
    if(i < 131008) cvt8(pos, posbf, i);        // 2047*512/8
  }
}

// ---- LayerNorm: 4 waves/block, one wave per row of 512, bf16 out ----
__global__ __launch_bounds__(256) void ln_kernel(const float* __restrict__ x,
    const float* __restrict__ w, const float* __restrict__ b, short* __restrict__ out){
  int row = blockIdx.x*4 + (threadIdx.x >> 6);
  int lane = threadIdx.x & 63;
  const float* xr = x + (size_t)row*512;
  f32x4 v0 = *(const f32x4*)(xr + lane*8);
  f32x4 v1 = *(const f32x4*)(xr + lane*8 + 4);
  float s  = v0[0]+v0[1]+v0[2]+v0[3]+v1[0]+v1[1]+v1[2]+v1[3];
  float s2 = v0[0]*v0[0]+v0[1]*v0[1]+v0[2]*v0[2]+v0[3]*v0[3]
           + v1[0]*v1[0]+v1[1]*v1[1]+v1[2]*v1[2]+v1[3]*v1[3];
  #pragma unroll
  for(int m=1;m<64;m<<=1){ s += __shfl_xor(s,m); s2 += __shfl_xor(s2,m); }
  float mu = s * (1.0f/512.0f);
  float rs = rsqrtf(s2*(1.0f/512.0f) - mu*mu + 1e-5f);
  short o[8];
  #pragma unroll
  for(int e=0;e<8;e++){
    float xv = (e<4)? v0[e] : v1[e-4];
    int d = lane*8 + e;
    o[e] = f2b((xv - mu)*rs*w[d] + b[d]);
  }
  *(s16x8*)(out + (size_t)row*512 + lane*8) = *(s16x8*)o;
}

// ---- generic GEMM: C[M,N] = A[M,K] @ B[N,K]^T (+bias) (+resid fp32 out) ----
template<int MODE>  // 0: bf16 out (+bias), 1: fp32 out (+bias+resid)
__global__ __launch_bounds__(256) void gemm_bt(
    const short* __restrict__ A, const short* __restrict__ B,
    const float* __restrict__ bias, const float* __restrict__ resid,
    void* __restrict__ Cout, int M, int N, int K, int Aclamp)
{
  __shared__ __align__(16) short At[128*32];
  __shared__ __align__(16) short Bt[128*32];
  int tid = threadIdx.x;
  int wave = tid >> 6, lane = tid & 63;
  int quad = lane >> 4, l16 = lane & 15;
  int wm = wave >> 1, wn = wave & 1;
  int m0 = blockIdx.y*128, n0 = blockIdx.x*128;
  int srow = lane >> 2, scol = (lane & 3)*8;
  f32x4 acc[4][4] = {};
  for(int k0=0; k0<K; k0+=32){
    #pragma unroll
    for(int c=0;c<2;c++){
      int r = wave*32 + c*16 + srow;
      int ra = m0 + r; if(ra > Aclamp-1) ra = Aclamp-1;
      gload_lds16(A + (size_t)ra*K + k0 + scol, At + (wave*32 + c*16)*32);
      gload_lds16(B + (size_t)(n0 + r)*K + k0 + scol, Bt + (wave*32 + c*16)*32);
    }
    __syncthreads();
    s16x8 af[4], bfr[4];
    #pragma unroll
    for(int i=0;i<4;i++) af[i]  = *(const s16x8*)(At + (wm*64 + i*16 + l16)*32 + quad*8);
    #pragma unroll
    for(int j=0;j<4;j++) bfr[j] = *(const s16x8*)(Bt + (wn*64 + j*16 + l16)*32 + quad*8);
    #pragma unroll
    for(int i=0;i<4;i++)
      #pragma unroll
      for(int j=0;j<4;j++)
        acc[i][j] = MFMA(af[i], bfr[j], acc[i][j]);
    __syncthreads();
  }
  #pragma unroll
  for(int i=0;i<4;i++){
    int rowb = m0 + wm*64 + i*16 + quad*4;
    #pragma unroll
    for(int j=0;j<4;j++){
      int col = n0 + wn*64 + j*16 + l16;
      float bv = bias ? bias[col] : 0.0f;
      #pragma unroll
      for(int r=0;r<4;r++){
        size_t idx = (size_t)(rowb + r)*N + col;
        float v = acc[i][j][r] + bv;
        if(MODE == 0) ((short*)Cout)[idx] = f2b(v);
        else          ((float*)Cout)[idx] = v + resid[idx];
      }
    }
  }
}

// ---- fused QKV GEMM: [8192,1536] = h @ [Wq;Wk;Wv]^T + b, row-major q/k/v out ----
__global__ __launch_bounds__(256) void gemm_qkv(
    const short* __restrict__ A, const short* __restrict__ B,
    const float* __restrict__ bq, const float* __restrict__ bk,
    const float* __restrict__ bv, short* __restrict__ qkv)  // q|k|v contiguous, 4M shorts apart
{
  __shared__ __align__(16) short At[128*32];
  __shared__ __align__(16) short Bt[128*32];
  int tid = threadIdx.x;
  int wave = tid >> 6, lane = tid & 63;
  int quad = lane >> 4, l16 = lane & 15;
  int wm = wave >> 1, wn = wave & 1;
  int m0 = blockIdx.y*128, n0 = blockIdx.x*128;
  int srow = lane >> 2, scol = (lane & 3)*8;
  f32x4 acc[4][4] = {};
  for(int k0=0; k0<512; k0+=32){
    #pragma unroll
    for(int c=0;c<2;c++){
      int r = wave*32 + c*16 + srow;
      gload_lds16(A + (size_t)(m0 + r)*512 + k0 + scol, At + (wave*32 + c*16)*32);
      gload_lds16(B + (size_t)(n0 + r)*512 + k0 + scol, Bt + (wave*32 + c*16)*32);
    }
    __syncthreads();
    s16x8 af[4], bfr[4];
    #pragma unroll
    for(int i=0;i<4;i++) af[i]  = *(const s16x8*)(At + (wm*64 + i*16 + l16)*32 + quad*8);
    #pragma unroll
    for(int j=0;j<4;j++) bfr[j] = *(const s16x8*)(Bt + (wn*64 + j*16 + l16)*32 + quad*8);
    #pragma unroll
    for(int i=0;i<4;i++)
      #pragma unroll
      for(int j=0;j<4;j++)
        acc[i][j] = MFMA(af[i], bfr[j], acc[i][j]);
    __syncthreads();
  }
  #pragma unroll
  for(int i=0;i<4;i++){
    int rowb = m0 + wm*64 + i*16 + quad*4;
    #pragma unroll
    for(int j=0;j<4;j++){
      int colg = n0 + wn*64 + j*16 + l16;
      int seg = colg >> 9, c = colg & 511;
      float bias = (seg == 0) ? bq[c] : (seg == 1) ? bk[c] : bv[c];
      short* dst = qkv + (size_t)seg*4194304;
      #pragma unroll
      for(int r=0;r<4;r++)
        dst[(size_t)(rowb + r)*512 + c] = f2b(acc[i][j][r] + bias);
    }
  }
}

// ---- repack k/p/v into fragment-major swizzled layouts ----
// k_sw chunk id: ((bh*64+jblk)*2+ks)*64+lane  -> k[b*1024+jblk*16+l16][h*64+ks*32+quad*8 ..+8]
// p_sw chunk id: ((h*128+rblk)*2+ks)*64+lane  -> p[rblk*16+l16][h*64+ks*32+quad*8 ..+8]
// v_sw chunk id: (((bh*16+jt)*4+ds)*2+jk)*64+lane -> V^T[ds*16+l16][jt*64+jk*32+quad*8 ..+8]
__global__ __launch_bounds__(256) void repack(
    const short* __restrict__ k, const short* __restrict__ p, const short* __restrict__ v,
    short* __restrict__ k_sw, short* __restrict__ p_sw, short* __restrict__ v_sw)
{
  int bid = blockIdx.x, tid = threadIdx.x;
  if(bid < 2048){                 // k: 524288 chunks
    size_t id = (size_t)bid*256 + tid;
    int lane = id & 63, ks = (id>>6)&1, jblk = (id>>7)&63, bh = id>>13;
    int b = bh>>3, h = bh&7, quad = lane>>4, l16 = lane&15;
    s16x8 vv = *(const s16x8*)(k + (size_t)(b*1024 + jblk*16 + l16)*512 + h*64 + ks*32 + quad*8);
    *(s16x8*)(k_sw + id*8) = vv;
  } else if(bid < 2560){          // p: 131072 chunks
    size_t id = (size_t)(bid-2048)*256 + tid;
    int lane = id & 63, ks = (id>>6)&1, rblk = (id>>7)&127, h = id>>14;
    int quad = lane>>4, l16 = lane&15;
    s16x8 vv = *(const s16x8*)(p + (size_t)(rblk*16 + l16)*512 + h*64 + ks*32 + quad*8);
    *(s16x8*)(p_sw + id*8) = vv;
  } else {                        // v: 1024 tiles of 64 tok x 64 dim, LDS transpose
    __shared__ __align__(16) short tile[64*72];   // dim-major [d][tok], stride 72
    int t = bid - 2560;
    int bh = t >> 4, jt = t & 15, b = bh>>3, h = bh&7;
    #pragma unroll
    for(int it=0; it<2; it++){
      int c = tid + it*256;
      int tok = c >> 3, dch = c & 7;
      s16x8 vv = *(const s16x8*)(v + (size_t)(b*1024 + jt*64 + tok)*512 + h*64 + dch*8);
      #pragma unroll
      for(int e=0;e<8;e++) tile[(dch*8+e)*72 + tok] = vv[e];
    }
    __syncthreads();
    #pragma unroll
    for(int it=0; it<2; it++){
      int c = tid + it*256;
      int ds = c >> 7, jk = (c>>6)&1, lane = c & 63;
      int quad = lane>>4, l16 = lane&15;
      s16x8 vv = *(const s16x8*)(tile + (ds*16 + l16)*72 + jk*32 + quad*8);
      *(s16x8*)(v_sw + ((size_t)(((bh*16+jt)*4+ds)*2+jk)*64 + lane)*8) = vv;
    }
  }
}

// ---- Fused rel-pos attention: 64 thr = 1 wave per block, 16 q-rows ----
// grid(64 qtiles, 8 heads, 8 batch). All global loads coalesced 1KB from *_sw.
// score(i,j) = [(q_i+u)·k_j + (q_i+v)·p_{j-i+1023}] * 0.125 (folded into q biases).
__global__ __launch_bounds__(64) void attn_kernel(
    const short* __restrict__ q, const short* __restrict__ k_sw, const short* __restrict__ v_sw,
    const short* __restrict__ p_sw, const float* __restrict__ bu, const float* __restrict__ bvv,
    short* __restrict__ out)
{
  __shared__ __align__(16) float psw[16*84];   // banded pos scores
  __shared__ __align__(16) short pw[16*72];    // P tile (PV A-layout source)
  int lane = threadIdx.x, quad = lane >> 4, l16 = lane & 15;
  int h = blockIdx.y, b = blockIdx.z, bh = b*8 + h;
  int iw = blockIdx.x * 16;

  // q fragments with (bias_u|bias_v) and 0.125 scale folded in
  size_t qbase = ((size_t)(b*1024 + iw + l16)*512) + h*64;
  s16x8 qu[2], qv[2];
  #pragma unroll
  for(int ks=0;ks<2;ks++){
    s16x8 qr = *(const s16x8*)(q + qbase + ks*32 + quad*8);
    short tu[8], tv[8];
    #pragma unroll
    for(int e=0;e<8;e++){
      int d = h*64 + ks*32 + quad*8 + e;
      float f = b2f(qr[e]);
      tu[e] = f2b((f + bu[d]) * 0.125f);
      tv[e] = f2b((f + bvv[d]) * 0.125f);
    }
    qu[ks] = *(s16x8*)tu; qv[ks] = *(s16x8*)tv;
  }

  f32x4 oacc[4] = {};
  float mrow[4], lrow[4];
  #pragma unroll
  for(int r=0;r<4;r++){ mrow[r] = -1e30f; lrow[r] = 0.0f; }

  const short* kb = k_sw + (size_t)bh*131072;            // 64*2*1024
  const short* vb = v_sw + (size_t)bh*131072;            // 16*4*2*1024
  const short* pb = p_sw + (size_t)h*262144;             // 128*2*1024

  #pragma unroll 2
  for(int jt=0; jt<16; jt++){
    int j0 = jt*64;
    // content scores: 4 j-subtiles x 2 k-steps, coalesced k_sw
    f32x4 sc[4];
    #pragma unroll
    for(int js=0;js<4;js++){
      f32x4 a = {};
      #pragma unroll
      for(int ks=0;ks<2;ks++){
        s16x8 kf = *(const s16x8*)(kb + ((size_t)((jt*4+js)*2+ks)*64 + lane)*8);
        a = MFMA(qu[ks], kf, a);
      }
      sc[js] = a;
    }
    // banded pos scores: rows r0..r0+79 (r0 multiple of 16), coalesced p_sw
    int rb0 = (j0 - iw + 1008) >> 4;
    #pragma unroll
    for(int nt=0;nt<5;nt++){
      f32x4 a = {};
      #pragma unroll
      for(int ks=0;ks<2;ks++){
        s16x8 pf = *(const s16x8*)(pb + ((size_t)((rb0+nt)*2+ks)*64 + lane)*8);
        a = MFMA(qv[ks], pf, a);
      }
      #pragma unroll
      for(int r=0;r<4;r++) psw[(quad*4+r)*84 + nt*16 + l16] = a[r];
    }
    // gather band (r_local = jl - il + 15), combine, online softmax
    float pvals[4][4];
    #pragma unroll
    for(int r=0;r<4;r++){
      int il = quad*4 + r;
      float mx = -1e30f;
      #pragma unroll
      for(int js=0;js<4;js++){
        int jl = js*16 + l16;
        float sv = sc[js][r] + psw[il*84 + (jl - il + 15)];
        pvals[js][r] = sv;
        mx = fmaxf(mx, sv);
      }
      #pragma unroll
      for(int m=1;m<16;m<<=1) mx = fmaxf(mx, __shfl_xor(mx, m));
      float mn = fmaxf(mrow[r], mx);
      float alpha = __expf(mrow[r] - mn);
      mrow[r] = mn;
      float ls = 0.0f;
      #pragma unroll
      for(int js=0;js<4;js++){
        float pe = __expf(pvals[js][r] - mn);
        pvals[js][r] = pe;
        ls += pe;
      }
      #pragma unroll
      for(int m=1;m<16;m<<=1) ls += __shfl_xor(ls, m);
      lrow[r] = lrow[r]*alpha + ls;
      #pragma unroll
      for(int ds=0;ds<4;ds++) oacc[ds][r] *= alpha;
    }
    // P -> LDS (PV A-layout source)
    #pragma unroll
    for(int js=0;js<4;js++)
      #pragma unroll
      for(int r=0;r<4;r++)
        pw[(quad*4+r)*72 + js*16 + l16] = f2b(pvals[js][r]);
    // PV: 2 j-ksteps x 4 d-subtiles, coalesced v_sw
    #pragma unroll
    for(int jk=0;jk<2;jk++){
      s16x8 pf = *(const s16x8*)(pw + l16*72 + jk*32 + quad*8);
      #pragma unroll
      for(int ds=0;ds<4;ds++){
        s16x8 vf = *(const s16x8*)(vb + ((size_t)((jt*4+ds)*2+jk)*64 + lane)*8);
        oacc[ds] = MFMA(pf, vf, oacc[ds]);
      }
    }
  }
  // epilogue: normalize, write bf16 [B,S,H,hd] == [8192,512]
  #pragma unroll
  for(int ds=0; ds<4; ds++){
    #pragma unroll
    for(int r=0;r<4;r++){
      int il = quad*4 + r;
      float ov = oacc[ds][r] / lrow[r];
      out[((size_t)(b*1024 + iw + il)*512) + h*64 + ds*16 + l16] = f2b(ov);
    }
  }
}

extern "C" void kernel_launch(void* const* d_in, const int* in_sizes, int n_in,
                              void* d_out, int out_size, void* d_ws, size_t ws_size,
                              hipStream_t stream)
{
  const float* x    = (const float*)d_in[0];
  const float* pos  = (const float*)d_in[1];
  const float* lnw  = (const float*)d_in[2];
  const float* lnb  = (const float*)d_in[3];
  const float* Wq   = (const float*)d_in[4];
  const float* bq   = (const float*)d_in[5];
  const float* Wk   = (const float*)d_in[6];
  const float* bk   = (const float*)d_in[7];
  const float* Wv   = (const float*)d_in[8];
  const float* bv   = (const float*)d_in[9];
  const float* Wo   = (const float*)d_in[10];
  const float* bo   = (const float*)d_in[11];
  const float* Wp   = (const float*)d_in[12];
  const float* pbu  = (const float*)d_in[13];
  const float* pbv  = (const float*)d_in[14];
  float* out = (float*)d_out;

  char* ws = (char*)d_ws;
  short* h_bf    = (short*)(ws);                 // 8192x512 (dead after gemm_qkv)
  short* q_bf    = (short*)(ws + ( 8u<<20));     // q|k|v contiguous row-major
  short* k_bf    = (short*)(ws + (16u<<20));
  short* v_bf    = (short*)(ws + (24u<<20));
  short* a_bf    = (short*)(ws + (32u<<20));
  short* p_bf    = (short*)(ws + (40u<<20));     // 2048x512 (padded)
  short* pos_bf  = (short*)(ws + (42u<<20));     // 2047x512 (dead after pos gemm)
  short* wqkv_bf = (short*)(ws + (44u<<20));     // [1536][512]
  short* wo_bf   = (short*)(ws + (46u<<20));
  short* wp_bf   = (short*)(ws + (47u<<20));
  short* k_sw    = (short*)(ws);                 // reuse h_bf region (8 MB)
  short* p_sw    = (short*)(ws + (42u<<20));     // reuse pos_bf region (2 MB)
  short* v_sw    = (short*)(ws + (48u<<20));     // 8 MB

  cvt_all<<<dim3(1152), 256, 0, stream>>>(Wq, Wk, Wv, Wo, Wp, pos,
                                          wqkv_bf, wo_bf, wp_bf, pos_bf);
  ln_kernel<<<dim3(2048), 256, 0, stream>>>(x, lnw, lnb, h_bf);
  gemm_qkv<<<dim3(12,64), 256, 0, stream>>>(h_bf, wqkv_bf, bq, bk, bv, q_bf);
  gemm_bt<0><<<dim3(4,16), 256, 0, stream>>>(pos_bf, wp_bf, nullptr, nullptr,
                                             p_bf, 2048,512,512, 2047);
  repack<<<dim3(3584), 256, 0, stream>>>(k_bf, p_bf, v_bf, k_sw, p_sw, v_sw);
  attn_kernel<<<dim3(64,8,8), 64, 0, stream>>>(q_bf, k_sw, v_sw, p_sw, pbu, pbv, a_bf);
  gemm_bt<1><<<dim3(4,64), 256, 0, stream>>>(a_bf, wo_bf, bo, x, out, 8192,512,512, 8192);
  (void)in_sizes; (void)n_in; (void)out_size; (void)ws_size;
}